// Round 2
// baseline (323.555 us; speedup 1.0000x reference)
//
#include <hip/hip_runtime.h>

// ---- problem constants ----
static constexpr int kR    = 896;
static constexpr int kLMAX = 510;
static constexpr int kWMAX = 509;
static constexpr int kHID  = 32;
static constexpr int kENC  = 10;
static constexpr int kGH   = 64;
static constexpr int kNCLS = 10;
static constexpr int kB    = 8;
static constexpr int kEPS  = 7168;
static constexpr int kN    = kB * kR;     // 7168 nodes
static constexpr int kE    = kB * kEPS;   // 57344 edges
static constexpr int kPAD  = 3 * 256 * 256; // 196608

// ---- workspace layout (floats) ----
static constexpr size_t OFF_EMB  = 0;
static constexpr size_t OFF_DEG  = OFF_EMB + (size_t)kN * kENC;
static constexpr size_t OFF_DINV = OFF_DEG + kN;
static constexpr size_t OFF_NORM = OFF_DINV + kN;
static constexpr size_t OFF_XW   = OFF_NORM + kE;
static constexpr size_t OFF_H1   = OFF_XW + (size_t)kN * kGH;
static constexpr size_t OFF_H2   = OFF_H1 + (size_t)kN * kGH;
static constexpr size_t OFF_VALS = OFF_H2 + (size_t)kN * kGH;   // [R][2][510][8]

__device__ __forceinline__ float sigmoidf_(float v) { return 1.0f / (1.0f + expf(-v)); }

// =====================================================================
// Kernel A: scattered gather x->vals_ws (linear), + edge-degree atomics.
// blocks [0,896): gather ring r. blocks [896, 896+224): deg atomics.
// =====================================================================
__global__ __launch_bounds__(256)
void k_gather(const float* __restrict__ x, const int* __restrict__ idx,
              const int* __restrict__ ei, const float* __restrict__ edge_w,
              float* __restrict__ vws, float* __restrict__ deg)
{
    const int bid = blockIdx.x;
    const int tid = threadIdx.x;
    if (bid < kR) {
        const int r = bid;
        for (int i = tid; i < 2 * kLMAX; i += 256) {
            const int hh = (i >= kLMAX) ? 1 : 0;
            const int li = i - hh * kLMAX;
            const int j = idx[(r * 2 + hh) * kLMAX + li];
            const bool ok = (unsigned)j < (unsigned)kPAD;
            float4 v0, v1;
            v0.x = ok ? x[(size_t)0 * kPAD + j] : 0.0f;
            v0.y = ok ? x[(size_t)1 * kPAD + j] : 0.0f;
            v0.z = ok ? x[(size_t)2 * kPAD + j] : 0.0f;
            v0.w = ok ? x[(size_t)3 * kPAD + j] : 0.0f;
            v1.x = ok ? x[(size_t)4 * kPAD + j] : 0.0f;
            v1.y = ok ? x[(size_t)5 * kPAD + j] : 0.0f;
            v1.z = ok ? x[(size_t)6 * kPAD + j] : 0.0f;
            v1.w = ok ? x[(size_t)7 * kPAD + j] : 0.0f;
            float4* dst = (float4*)&vws[((size_t)(r * 2 + hh) * kLMAX + li) * 8];
            dst[0] = v0; dst[1] = v1;
        }
    } else {
        const int e = (bid - kR) * 256 + tid;
        if (e < kE) {
            const int t = ei[kE + e];
            atomicAdd(&deg[t], sigmoidf_(edge_w[e % kEPS]));
        }
    }
}

// =====================================================================
// Kernel 1: fused conv + decoder contraction, Wdec register-prefetched.
// grid = 1792 blocks: (r, half). block = 320 threads = 5 waves,
// each wave owns 2 output channels o. 16 phases (4 w-tiles x 4 c-tiles),
// fully unrolled with depth-2 register double-buffer on Wdec.
// LDS ~41.7 KB -> 3 blocks/CU (15 waves/CU).
// =====================================================================
__global__ __launch_bounds__(320, 4)
void k_conv_emb(const float* __restrict__ vws,
                const float* __restrict__ Wconv, const float* __restrict__ bconv,
                const float* __restrict__ Wdec, float* __restrict__ emb)
{
    const int r    = blockIdx.x >> 1;
    const int half = blockIdx.x & 1;
    const int l0   = half ? 256 : 0;
    const int lcnt = half ? (kLMAX - 256) : 257;   // 254 : 257
    const int w0   = half ? 256 : 0;
    const int wtot = half ? (kWMAX - 256) : 256;   // 253 : 256

    __shared__ float vals[2][kB][257];
    __shared__ __align__(16) float htile[8][64][12];
    __shared__ float wconv_s[kHID * 4];
    __shared__ float bconv_s[kHID];

    const int tid  = threadIdx.x;
    const int wave = tid >> 6;
    const int lane = tid & 63;
    const int o0 = wave * 2, o1 = o0 + 1;
    const float* WdR = Wdec + (size_t)r * kENC * kHID * kWMAX;

    // ---- issue Wdec prefetch for phases 0,1 ASAP ----
    float buf0[16], buf1[16];
    {
        // phase p: ck = p>>2 (w-tile), ct = p&3 (c-tile)
        const int wg0 = min(w0 + 0 * 64 + lane, kWMAX - 1);
        const float* b0 = WdR + (size_t)(o0 * kHID + 0) * kWMAX + wg0;
        const float* b1 = WdR + (size_t)(o1 * kHID + 0) * kWMAX + wg0;
        #pragma unroll
        for (int cc = 0; cc < 8; ++cc) {
            buf0[cc]     = b0[(size_t)cc * kWMAX];
            buf0[8 + cc] = b1[(size_t)cc * kWMAX];
        }
        const float* c0p = WdR + (size_t)(o0 * kHID + 8) * kWMAX + wg0;
        const float* c1p = WdR + (size_t)(o1 * kHID + 8) * kWMAX + wg0;
        #pragma unroll
        for (int cc = 0; cc < 8; ++cc) {
            buf1[cc]     = c0p[(size_t)cc * kWMAX];
            buf1[8 + cc] = c1p[(size_t)cc * kWMAX];
        }
    }

    // ---- stage Wconv/bconv + vals (coalesced float4 from vws) ----
    for (int i = tid; i < kHID * 4; i += 320) wconv_s[i] = Wconv[r * kHID * 4 + i];
    if (tid < kHID) bconv_s[tid] = bconv[r * kHID + tid];

    for (int hh = 0; hh < 2; ++hh) {
        for (int i = tid; i < lcnt * 2; i += 320) {
            const int li = i >> 1, q = i & 1;
            const float4 v = *(const float4*)&vws[((size_t)(r * 2 + hh) * kLMAX + l0 + li) * 8 + q * 4];
            vals[hh][q * 4 + 0][li] = v.x;
            vals[hh][q * 4 + 1][li] = v.y;
            vals[hh][q * 4 + 2][li] = v.z;
            vals[hh][q * 4 + 3][li] = v.w;
        }
    }

    float acc0[8], acc1[8];
    #pragma unroll
    for (int b = 0; b < 8; ++b) { acc0[b] = 0.0f; acc1[b] = 0.0f; }

    #pragma unroll
    for (int p = 0; p < 16; ++p) {
        const int ck = p >> 2, ct = p & 3;
        const int wb   = w0 + ck * 64;
        const int wcnt = min(64, w0 + wtot - wb);
        const int c0   = ct * 8;

        __syncthreads();   // all waves done reading htile from phase p-1
        // ---- compute h tile ----
        for (int i = tid; i < 512; i += 320) {
            const int wl = i >> 3, b = i & 7;
            float v00 = 0, v01 = 0, v10 = 0, v11 = 0;
            if (wl < wcnt) {
                const int base = wb - l0 + wl;
                v00 = vals[0][b][base]; v01 = vals[0][b][base + 1];
                v10 = vals[1][b][base]; v11 = vals[1][b][base + 1];
            }
            #pragma unroll
            for (int cc = 0; cc < 8; ++cc) {
                const float* wc = &wconv_s[(c0 + cc) * 4];
                float h = fmaf(v00, wc[0], fmaf(v01, wc[1],
                          fmaf(v10, wc[2], fmaf(v11, wc[3], bconv_s[c0 + cc]))));
                h = (wl < wcnt) ? fmaxf(h, 0.0f) : 0.0f;
                htile[cc][wl][b] = h;
            }
        }
        __syncthreads();

        // ---- consume current buffer ----
        float* cur = (p & 1) ? buf1 : buf0;
        #pragma unroll
        for (int cc = 0; cc < 8; ++cc) {
            const float4* hp = (const float4*)&htile[cc][lane][0];
            const float4 ha = hp[0], hb = hp[1];
            const float hv[8] = {ha.x, ha.y, ha.z, ha.w, hb.x, hb.y, hb.z, hb.w};
            const float wd0 = cur[cc], wd1 = cur[8 + cc];
            #pragma unroll
            for (int b = 0; b < 8; ++b) {
                acc0[b] = fmaf(wd0, hv[b], acc0[b]);
                acc1[b] = fmaf(wd1, hv[b], acc1[b]);
            }
        }

        // ---- prefetch phase p+2 into the buffer just consumed ----
        if (p < 14) {
            const int pn = p + 2;
            const int nck = pn >> 2, nct = pn & 3;
            const int nwb = w0 + nck * 64;
            const int wg  = min(nwb + lane, kWMAX - 1);
            const float* a0 = WdR + (size_t)(o0 * kHID + nct * 8) * kWMAX + wg;
            const float* a1 = WdR + (size_t)(o1 * kHID + nct * 8) * kWMAX + wg;
            #pragma unroll
            for (int cc = 0; cc < 8; ++cc) {
                cur[cc]     = a0[(size_t)cc * kWMAX];
                cur[8 + cc] = a1[(size_t)cc * kWMAX];
            }
        }
    }

    // ---- wave-reduce + atomic accumulate into emb ----
    #pragma unroll
    for (int b = 0; b < 8; ++b) {
        float s0 = acc0[b], s1 = acc1[b];
        #pragma unroll
        for (int sft = 32; sft > 0; sft >>= 1) {
            s0 += __shfl_xor(s0, sft);
            s1 += __shfl_xor(s1, sft);
        }
        if (lane == 0) {
            atomicAdd(&emb[(size_t)(b * kR + r) * kENC + o0], s0);
            atomicAdd(&emb[(size_t)(b * kR + r) * kENC + o1], s1);
        }
    }
}

// =====================================================================
// GCN kernels
// =====================================================================
__global__ void k_dinv(const float* __restrict__ deg, float* __restrict__ dinv)
{
    int i = blockIdx.x * 256 + threadIdx.x;
    if (i < kN) dinv[i] = rsqrtf(deg[i] + 1.0f);   // +1 = self loop
}

__global__ void k_norm(const int* __restrict__ ei, const float* __restrict__ edge_w,
                       const float* __restrict__ dinv, float* __restrict__ norm)
{
    int e = blockIdx.x * 256 + threadIdx.x;
    if (e >= kE) return;
    norm[e] = dinv[ei[e]] * sigmoidf_(edge_w[e % kEPS]) * dinv[ei[kE + e]];
}

// xw1 = (emb + bdec) @ Wg1 ; h1 init = bg1 + dinv^2 * xw1
__global__ void k_xw1(const float* __restrict__ emb, const float* __restrict__ bdec,
                      const float* __restrict__ Wg1, const float* __restrict__ bg1,
                      const float* __restrict__ dinv,
                      float* __restrict__ xw1, float* __restrict__ h1)
{
    int t = blockIdx.x * 256 + threadIdx.x;
    int i = t >> 6, f = t & 63;
    int r = i % kR;
    float s = 0.0f;
    #pragma unroll
    for (int o = 0; o < kENC; ++o)
        s = fmaf(emb[i * kENC + o] + bdec[r * kENC + o], Wg1[o * kGH + f], s);
    xw1[t] = s;
    float di = dinv[i];
    h1[t] = bg1[f] + di * di * s;
}

__global__ void k_scatter(const int* __restrict__ ei, const float* __restrict__ norm,
                          const float* __restrict__ xw, float* __restrict__ h)
{
    int t = blockIdx.x * 256 + threadIdx.x;
    int e = t >> 6, f = t & 63;
    float nm = norm[e];
    atomicAdd(&h[(size_t)ei[kE + e] * kGH + f], nm * xw[(size_t)ei[e] * kGH + f]);
}

// xw2 = relu(h1) @ Wg2 ; h2 init = bg2 + dinv^2 * xw2
__global__ void k_xw2(const float* __restrict__ h1, const float* __restrict__ Wg2,
                      const float* __restrict__ bg2, const float* __restrict__ dinv,
                      float* __restrict__ xw2, float* __restrict__ h2)
{
    int t = blockIdx.x * 256 + threadIdx.x;
    int i = t >> 6, g = t & 63;
    float s = 0.0f;
    for (int f = 0; f < kGH; ++f)
        s = fmaf(fmaxf(h1[i * kGH + f], 0.0f), Wg2[f * kGH + g], s);
    xw2[t] = s;
    float di = dinv[i];
    h2[t] = bg2[g] + di * di * s;
}

__global__ void k_head(const float* __restrict__ h2, const float* __restrict__ Wl,
                       const float* __restrict__ bl, float* __restrict__ out)
{
    int b = blockIdx.x;
    int t = threadIdx.x;           // 256
    int g = t & 63, part = t >> 6; // 4 parts
    float s = 0.0f;
    for (int r = part; r < kR; r += 4)
        s += h2[(size_t)(b * kR + r) * kGH + g];
    __shared__ float red[4][64];
    __shared__ float pooled[64];
    __shared__ float lg[kNCLS];
    red[part][g] = s;
    __syncthreads();
    if (t < 64) pooled[t] = (red[0][t] + red[1][t] + red[2][t] + red[3][t]) * (1.0f / kR);
    __syncthreads();
    if (t < kNCLS) {
        float s2 = bl[t];
        for (int gg = 0; gg < kGH; ++gg) s2 = fmaf(pooled[gg], Wl[gg * kNCLS + t], s2);
        lg[t] = s2;
    }
    __syncthreads();
    if (t == 0) {
        float mx = lg[0];
        for (int j = 1; j < kNCLS; ++j) mx = fmaxf(mx, lg[j]);
        float ssum = 0.0f, ex[kNCLS];
        for (int j = 0; j < kNCLS; ++j) { ex[j] = expf(lg[j] - mx); ssum += ex[j]; }
        for (int j = 0; j < kNCLS; ++j) out[b * kNCLS + j] = ex[j] / ssum;
    }
}

extern "C" void kernel_launch(void* const* d_in, const int* in_sizes, int n_in,
                              void* d_out, int out_size, void* d_ws, size_t ws_size,
                              hipStream_t stream)
{
    const float* x      = (const float*)d_in[0];
    const int*   ei     = (const int*)d_in[1];
    const int*   idx    = (const int*)d_in[3];
    const float* Wconv  = (const float*)d_in[4];
    const float* bconv  = (const float*)d_in[5];
    const float* Wdec   = (const float*)d_in[6];
    const float* bdec   = (const float*)d_in[7];
    const float* edge_w = (const float*)d_in[8];
    const float* Wg1    = (const float*)d_in[9];
    const float* bg1    = (const float*)d_in[10];
    const float* Wg2    = (const float*)d_in[11];
    const float* bg2    = (const float*)d_in[12];
    const float* Wl     = (const float*)d_in[13];
    const float* bl     = (const float*)d_in[14];

    float* ws   = (float*)d_ws;
    float* emb  = ws + OFF_EMB;
    float* deg  = ws + OFF_DEG;
    float* dinv = ws + OFF_DINV;
    float* norm = ws + OFF_NORM;
    float* xw   = ws + OFF_XW;
    float* h1   = ws + OFF_H1;
    float* h2   = ws + OFF_H2;
    float* vws  = ws + OFF_VALS;

    hipMemsetAsync(emb, 0, (size_t)kN * kENC * sizeof(float), stream);
    hipMemsetAsync(deg, 0, (size_t)kN * sizeof(float), stream);

    k_gather<<<kR + (kE + 255) / 256, 256, 0, stream>>>(x, idx, ei, edge_w, vws, deg);

    k_conv_emb<<<kR * 2, 320, 0, stream>>>(vws, Wconv, bconv, Wdec, emb);

    k_dinv<<<(kN + 255) / 256, 256, 0, stream>>>(deg, dinv);
    k_norm<<<(kE + 255) / 256, 256, 0, stream>>>(ei, edge_w, dinv, norm);

    k_xw1<<<kN * kGH / 256, 256, 0, stream>>>(emb, bdec, Wg1, bg1, dinv, xw, h1);
    k_scatter<<<kE * kGH / 256, 256, 0, stream>>>(ei, norm, xw, h1);
    k_xw2<<<kN * kGH / 256, 256, 0, stream>>>(h1, Wg2, bg2, dinv, xw, h2);
    k_scatter<<<kE * kGH / 256, 256, 0, stream>>>(ei, norm, xw, h2);

    k_head<<<kB, 256, 0, stream>>>(h2, Wl, bl, (float*)d_out);
}

// Round 3
// 165.006 us; speedup vs baseline: 1.9609x; 1.9609x over previous
//
#include <hip/hip_runtime.h>

// ---- problem constants ----
static constexpr int kR    = 896;
static constexpr int kLMAX = 510;
static constexpr int kWMAX = 509;
static constexpr int kHID  = 32;
static constexpr int kENC  = 10;
static constexpr int kGH   = 64;
static constexpr int kNCLS = 10;
static constexpr int kB    = 8;
static constexpr int kEPS  = 7168;
static constexpr int kN    = kB * kR;
static constexpr int kE    = kB * kEPS;
static constexpr int kPAD  = 3 * 256 * 256;

// band[r] = 4*i+1, i = ring index within its (m, by, bx) block.
constexpr int band_of(int r) {
    int i = (r < 128) ? r : (r < 384) ? ((r - 128) & 63) : ((r - 384) & 31);
    return 4 * i + 1;
}
__device__ __forceinline__ int band_dev(int r) {
    int i = (r < 128) ? r : (r < 384) ? ((r - 128) & 63) : ((r - 384) & 31);
    return 4 * i + 1;
}

// compile-time chunk table: (r, w0) with w0 stepping by 128 up to band[r]
static constexpr int kCHUNK = 128;
constexpr int count_chunks() {
    int n = 0;
    for (int r = 0; r < kR; ++r) n += (band_of(r) + kCHUNK - 1) / kCHUNK;
    return n;
}
static constexpr int kNCHUNK = count_chunks();   // = 1216
static_assert(kNCHUNK == 1216, "chunk count");

struct CE { short r; short w0; };
struct Tab { CE e[kNCHUNK]; };
constexpr Tab make_tab() {
    Tab t{};
    int n = 0;
    for (int r = 0; r < kR; ++r)
        for (int w0 = 0; w0 < band_of(r); w0 += kCHUNK) {
            t.e[n].r = (short)r; t.e[n].w0 = (short)w0; ++n;
        }
    return t;
}
__device__ __constant__ Tab g_tab = make_tab();

// ---- workspace layout (floats) ----
static constexpr size_t OFF_EMB  = 0;
static constexpr size_t OFF_DEG  = OFF_EMB + (size_t)kN * kENC;
static constexpr size_t OFF_DINV = OFF_DEG + kN;
static constexpr size_t OFF_CSUM = OFF_DINV + kN;
static constexpr size_t OFF_NORM = OFF_CSUM + kN;
static constexpr size_t OFF_XW1  = OFF_NORM + kE;
static constexpr size_t OFF_H1   = OFF_XW1 + (size_t)kN * kGH;
static constexpr size_t OFF_XW2  = OFF_H1 + (size_t)kN * kGH;

__device__ __forceinline__ float sigmoidf_(float v) { return 1.0f / (1.0f + expf(-v)); }

// =====================================================================
// Kernel 1: band-aware fused conv + decoder. One block per (r, w-chunk).
// 320 threads = 5 waves; wave owns output-channel pair (o0, o0+1);
// lane owns w within a 64-wide subtile. No barriers in the main loop.
// Extra blocks [kNCHUNK, ...) do the edge-degree atomics.
// =====================================================================
__global__ __launch_bounds__(320, 4)
void k_conv_emb(const float* __restrict__ x, const int* __restrict__ idx,
                const float* __restrict__ Wconv, const float* __restrict__ bconv,
                const float* __restrict__ Wdec,
                const int* __restrict__ ei, const float* __restrict__ edge_w,
                float* __restrict__ emb, float* __restrict__ deg)
{
    const int bid = blockIdx.x;
    const int tid = threadIdx.x;
    if (bid >= kNCHUNK) {
        const int e = (bid - kNCHUNK) * 320 + tid;
        if (e < kE) atomicAdd(&deg[ei[kE + e]], sigmoidf_(edge_w[e % kEPS]));
        return;
    }

    const int r     = g_tab.e[bid].r;
    const int w0    = g_tab.e[bid].w0;
    const int bandr = band_dev(r);
    const int wc    = min(kCHUNK, bandr - w0);   // valid w in [w0, w0+wc)

    __shared__ float vals[2][kB][kCHUNK + 1];
    __shared__ float wconv_s[kHID * 4];
    __shared__ float bconv_s[kHID];

    if (tid < 128) wconv_s[tid] = Wconv[r * 128 + tid];
    else if (tid < 160) bconv_s[tid - 128] = bconv[r * kHID + (tid - 128)];

    // gather x for this chunk (window needs indices w0 .. w0+wc)
    for (int i = tid; i < 2 * (kCHUNK + 1); i += 320) {
        const int hh = i >= (kCHUNK + 1);
        const int li = i - hh * (kCHUNK + 1);
        const int j = (li <= wc) ? idx[(r * 2 + hh) * kLMAX + w0 + li] : kPAD;
        const bool ok = (unsigned)j < (unsigned)kPAD;
        #pragma unroll
        for (int b = 0; b < kB; ++b)
            vals[hh][b][li] = ok ? x[(size_t)b * kPAD + j] : 0.0f;
    }
    __syncthreads();

    const int wave = tid >> 6, lane = tid & 63;
    const int o0 = wave * 2;
    const float* Wd0 = Wdec + ((size_t)(r * kENC + o0) * kHID) * kWMAX;
    const float* Wd1 = Wd0 + (size_t)kHID * kWMAX;

    float acc0[8] = {0,0,0,0,0,0,0,0}, acc1[8] = {0,0,0,0,0,0,0,0};

    #pragma unroll
    for (int st = 0; st < 2; ++st) {
        const int wl = st * 64 + lane;
        if (st * 64 >= wc) break;              // uniform: whole block skips
        const bool valid = (wl < wc);
        const int w = w0 + wl;

        float v00[8], v01[8], v10[8], v11[8];
        #pragma unroll
        for (int b = 0; b < 8; ++b) {
            v00[b] = vals[0][b][wl]; v01[b] = vals[0][b][wl + 1];
            v10[b] = vals[1][b][wl]; v11[b] = vals[1][b][wl + 1];
        }

        #pragma unroll 8
        for (int c = 0; c < kHID; ++c) {
            const float wd0 = valid ? Wd0[(size_t)c * kWMAX + w] : 0.0f;
            const float wd1 = valid ? Wd1[(size_t)c * kWMAX + w] : 0.0f;
            const float w00 = wconv_s[c * 4 + 0], w01 = wconv_s[c * 4 + 1];
            const float w10 = wconv_s[c * 4 + 2], w11 = wconv_s[c * 4 + 3];
            const float bc  = bconv_s[c];
            #pragma unroll
            for (int b = 0; b < 8; ++b) {
                float h = fmaf(v00[b], w00, fmaf(v01[b], w01,
                          fmaf(v10[b], w10, fmaf(v11[b], w11, bc))));
                h = fmaxf(h, 0.0f);
                acc0[b] = fmaf(wd0, h, acc0[b]);
                acc1[b] = fmaf(wd1, h, acc1[b]);
            }
        }
    }

    #pragma unroll
    for (int b = 0; b < 8; ++b) {
        float s0 = acc0[b], s1 = acc1[b];
        #pragma unroll
        for (int sft = 32; sft > 0; sft >>= 1) {
            s0 += __shfl_xor(s0, sft);
            s1 += __shfl_xor(s1, sft);
        }
        if (lane == 0) {
            atomicAdd(&emb[((size_t)b * kR + r) * kENC + o0],     s0);
            atomicAdd(&emb[((size_t)b * kR + r) * kENC + o0 + 1], s1);
        }
    }
}

// =====================================================================
// GCN kernels
// =====================================================================
__global__ void k_dinv(const float* __restrict__ deg, float* __restrict__ dinv,
                       float* __restrict__ colsum)
{
    int i = blockIdx.x * 256 + threadIdx.x;
    if (i < kN) {
        float d = deg[i] + 1.0f;            // self loop
        dinv[i] = rsqrtf(d);
        colsum[i] = 1.0f / d;               // dinv^2 (self-loop col term)
    }
}

__global__ void k_norm(const int* __restrict__ ei, const float* __restrict__ edge_w,
                       const float* __restrict__ dinv, float* __restrict__ norm,
                       float* __restrict__ colsum)
{
    int e = blockIdx.x * 256 + threadIdx.x;
    if (e >= kE) return;
    int s = ei[e];
    float nm = dinv[s] * sigmoidf_(edge_w[e % kEPS]) * dinv[ei[kE + e]];
    norm[e] = nm;
    atomicAdd(&colsum[s], nm);              // layer-2 column sums
}

// xw1 = (emb + bdec) @ Wg1 ; h1 init = bg1 + dinv^2 * xw1
__global__ void k_xw1(const float* __restrict__ emb, const float* __restrict__ bdec,
                      const float* __restrict__ Wg1, const float* __restrict__ bg1,
                      const float* __restrict__ dinv,
                      float* __restrict__ xw1, float* __restrict__ h1)
{
    int t = blockIdx.x * 256 + threadIdx.x;
    int i = t >> 6, f = t & 63;
    int r = i % kR;
    float s = 0.0f;
    #pragma unroll
    for (int o = 0; o < kENC; ++o)
        s = fmaf(emb[i * kENC + o] + bdec[r * kENC + o], Wg1[o * kGH + f], s);
    xw1[t] = s;
    float di = dinv[i];
    h1[t] = bg1[f] + di * di * s;
}

__global__ void k_scatter(const int* __restrict__ ei, const float* __restrict__ norm,
                          const float* __restrict__ xw, float* __restrict__ h)
{
    int t = blockIdx.x * 256 + threadIdx.x;
    int e = t >> 6, f = t & 63;
    float nm = norm[e];
    atomicAdd(&h[(size_t)ei[kE + e] * kGH + f], nm * xw[(size_t)ei[e] * kGH + f]);
}

// xw2 = relu(h1) @ Wg2
__global__ void k_xw2(const float* __restrict__ h1, const float* __restrict__ Wg2,
                      float* __restrict__ xw2)
{
    int t = blockIdx.x * 256 + threadIdx.x;
    int i = t >> 6, g = t & 63;
    float s = 0.0f;
    for (int f = 0; f < kGH; ++f)
        s = fmaf(fmaxf(h1[i * kGH + f], 0.0f), Wg2[f * kGH + g], s);
    xw2[t] = s;
}

// pooled_b = bg2 + (1/R) * sum_j colsum_j * xw2_j ; head + softmax
__global__ void k_pool(const float* __restrict__ xw2, const float* __restrict__ colsum,
                       const float* __restrict__ bg2, const float* __restrict__ Wl,
                       const float* __restrict__ bl, float* __restrict__ out)
{
    int b = blockIdx.x;
    int t = threadIdx.x;           // 256
    int g = t & 63, part = t >> 6;
    float s = 0.0f;
    for (int rr = part; rr < kR; rr += 4) {
        int j = b * kR + rr;
        s = fmaf(colsum[j], xw2[(size_t)j * kGH + g], s);
    }
    __shared__ float red[4][64];
    __shared__ float pooled[64];
    __shared__ float lg[kNCLS];
    red[part][g] = s;
    __syncthreads();
    if (t < 64)
        pooled[t] = bg2[t] + (red[0][t] + red[1][t] + red[2][t] + red[3][t]) * (1.0f / kR);
    __syncthreads();
    if (t < kNCLS) {
        float s2 = bl[t];
        for (int gg = 0; gg < kGH; ++gg) s2 = fmaf(pooled[gg], Wl[gg * kNCLS + t], s2);
        lg[t] = s2;
    }
    __syncthreads();
    if (t == 0) {
        float mx = lg[0];
        for (int j = 1; j < kNCLS; ++j) mx = fmaxf(mx, lg[j]);
        float ssum = 0.0f, ex[kNCLS];
        for (int j = 0; j < kNCLS; ++j) { ex[j] = expf(lg[j] - mx); ssum += ex[j]; }
        for (int j = 0; j < kNCLS; ++j) out[b * kNCLS + j] = ex[j] / ssum;
    }
}

extern "C" void kernel_launch(void* const* d_in, const int* in_sizes, int n_in,
                              void* d_out, int out_size, void* d_ws, size_t ws_size,
                              hipStream_t stream)
{
    const float* x      = (const float*)d_in[0];
    const int*   ei     = (const int*)d_in[1];
    const int*   idx    = (const int*)d_in[3];
    const float* Wconv  = (const float*)d_in[4];
    const float* bconv  = (const float*)d_in[5];
    const float* Wdec   = (const float*)d_in[6];
    const float* bdec   = (const float*)d_in[7];
    const float* edge_w = (const float*)d_in[8];
    const float* Wg1    = (const float*)d_in[9];
    const float* bg1    = (const float*)d_in[10];
    const float* Wg2    = (const float*)d_in[11];
    const float* bg2    = (const float*)d_in[12];
    const float* Wl     = (const float*)d_in[13];
    const float* bl     = (const float*)d_in[14];

    float* ws     = (float*)d_ws;
    float* emb    = ws + OFF_EMB;
    float* deg    = ws + OFF_DEG;
    float* dinv   = ws + OFF_DINV;
    float* colsum = ws + OFF_CSUM;
    float* norm   = ws + OFF_NORM;
    float* xw1    = ws + OFF_XW1;
    float* h1     = ws + OFF_H1;
    float* xw2    = ws + OFF_XW2;

    hipMemsetAsync(emb, 0, (size_t)kN * kENC * sizeof(float), stream);
    hipMemsetAsync(deg, 0, (size_t)kN * sizeof(float), stream);

    const int degBlocks = (kE + 319) / 320;
    k_conv_emb<<<kNCHUNK + degBlocks, 320, 0, stream>>>(x, idx, Wconv, bconv, Wdec,
                                                        ei, edge_w, emb, deg);

    k_dinv<<<(kN + 255) / 256, 256, 0, stream>>>(deg, dinv, colsum);
    k_norm<<<(kE + 255) / 256, 256, 0, stream>>>(ei, edge_w, dinv, norm, colsum);

    k_xw1<<<kN * kGH / 256, 256, 0, stream>>>(emb, bdec, Wg1, bg1, dinv, xw1, h1);
    k_scatter<<<kE * kGH / 256, 256, 0, stream>>>(ei, norm, xw1, h1);
    k_xw2<<<kN * kGH / 256, 256, 0, stream>>>(h1, Wg2, xw2);

    k_pool<<<kB, 256, 0, stream>>>(xw2, colsum, bg2, Wl, bl, (float*)d_out);
}

// Round 4
// 128.394 us; speedup vs baseline: 2.5200x; 1.2852x over previous
//
#include <hip/hip_runtime.h>

// ---- problem constants ----
static constexpr int kR    = 896;
static constexpr int kLMAX = 510;
static constexpr int kWMAX = 509;
static constexpr int kHID  = 32;
static constexpr int kENC  = 10;
static constexpr int kGH   = 64;
static constexpr int kNCLS = 10;
static constexpr int kB    = 8;
static constexpr int kEPS  = 7168;
static constexpr int kN    = kB * kR;
static constexpr int kE    = kB * kEPS;
static constexpr int kPAD  = 3 * 256 * 256;

// band[r] = 4*i+1, i = ring index within its (m, by, bx) block.
constexpr int band_of(int r) {
    int i = (r < 128) ? r : (r < 384) ? ((r - 128) & 63) : ((r - 384) & 31);
    return 4 * i + 1;
}
__device__ __forceinline__ int band_dev(int r) {
    int i = (r < 128) ? r : (r < 384) ? ((r - 128) & 63) : ((r - 384) & 31);
    return 4 * i + 1;
}

static constexpr int kCHUNK = 128;
constexpr int count_chunks() {
    int n = 0;
    for (int r = 0; r < kR; ++r) n += (band_of(r) + kCHUNK - 1) / kCHUNK;
    return n;
}
static constexpr int kNCHUNK = count_chunks();   // 1216
static_assert(kNCHUNK == 1216, "chunk count");

struct CE { short r; short w0; };
struct Tab { CE e[kNCHUNK]; };
constexpr Tab make_tab() {
    Tab t{};
    int n = 0;
    for (int r = 0; r < kR; ++r)
        for (int w0 = 0; w0 < band_of(r); w0 += kCHUNK) {
            t.e[n].r = (short)r; t.e[n].w0 = (short)w0; ++n;
        }
    return t;
}
__device__ __constant__ Tab g_tab = make_tab();

// ---- workspace layout (floats; ints stored in same region) ----
static constexpr size_t OFF_EMB  = 0;                       // 71680 f
static constexpr size_t OFF_DEG  = OFF_EMB + 71680;         // 7168 f
static constexpr size_t OFF_CNT  = OFF_DEG + 7168;          // 7168 int
static constexpr size_t OFF_POOL = OFF_CNT + 7168;          // 512 f
static constexpr size_t kMEMSET_FLOATS = OFF_POOL + 512;    // 86528 (zeroed)
static constexpr size_t OFF_DINV = kMEMSET_FLOATS;          // 7168 f
static constexpr size_t OFF_CSUM = OFF_DINV + 7168;         // 7168 f
static constexpr size_t OFF_OFFS = OFF_CSUM + 7168;         // 7169 int
static constexpr size_t OFF_WOFF = OFF_OFFS + 7169;         // 7169 int
static constexpr size_t OFF_CSRC = OFF_WOFF + 7169;         // 57344 int
static constexpr size_t OFF_CNRM = OFF_CSRC + 57344;        // 57344 f
static constexpr size_t OFF_XW1  = OFF_CNRM + 57344;        // 458752 f

__device__ __forceinline__ float sigmoidf_(float v) { return 1.0f / (1.0f + expf(-v)); }

// =====================================================================
// Kernel 1: band-aware fused conv + decoder (unchanged from R3) +
// spare blocks do per-edge degree-sum (float) and in-degree count (int).
// =====================================================================
__global__ __launch_bounds__(320, 4)
void k_conv_emb(const float* __restrict__ x, const int* __restrict__ idx,
                const float* __restrict__ Wconv, const float* __restrict__ bconv,
                const float* __restrict__ Wdec,
                const int* __restrict__ ei, const float* __restrict__ edge_w,
                float* __restrict__ emb, float* __restrict__ deg, int* __restrict__ cnt)
{
    const int bid = blockIdx.x;
    const int tid = threadIdx.x;
    if (bid >= kNCHUNK) {
        const int e = (bid - kNCHUNK) * 320 + tid;
        if (e < kE) {
            const int t = ei[kE + e];
            atomicAdd(&deg[t], sigmoidf_(edge_w[e % kEPS]));
            atomicAdd(&cnt[t], 1);
        }
        return;
    }

    const int r     = g_tab.e[bid].r;
    const int w0    = g_tab.e[bid].w0;
    const int bandr = band_dev(r);
    const int wc    = min(kCHUNK, bandr - w0);

    __shared__ float vals[2][kB][kCHUNK + 1];
    __shared__ float wconv_s[kHID * 4];
    __shared__ float bconv_s[kHID];

    if (tid < 128) wconv_s[tid] = Wconv[r * 128 + tid];
    else if (tid < 160) bconv_s[tid - 128] = bconv[r * kHID + (tid - 128)];

    for (int i = tid; i < 2 * (kCHUNK + 1); i += 320) {
        const int hh = i >= (kCHUNK + 1);
        const int li = i - hh * (kCHUNK + 1);
        const int j = (li <= wc) ? idx[(r * 2 + hh) * kLMAX + w0 + li] : kPAD;
        const bool ok = (unsigned)j < (unsigned)kPAD;
        #pragma unroll
        for (int b = 0; b < kB; ++b)
            vals[hh][b][li] = ok ? x[(size_t)b * kPAD + j] : 0.0f;
    }
    __syncthreads();

    const int wave = tid >> 6, lane = tid & 63;
    const int o0 = wave * 2;
    const float* Wd0 = Wdec + ((size_t)(r * kENC + o0) * kHID) * kWMAX;
    const float* Wd1 = Wd0 + (size_t)kHID * kWMAX;

    float acc0[8] = {0,0,0,0,0,0,0,0}, acc1[8] = {0,0,0,0,0,0,0,0};

    #pragma unroll
    for (int st = 0; st < 2; ++st) {
        const int wl = st * 64 + lane;
        if (st * 64 >= wc) break;
        const bool valid = (wl < wc);
        const int w = w0 + wl;

        float v00[8], v01[8], v10[8], v11[8];
        #pragma unroll
        for (int b = 0; b < 8; ++b) {
            v00[b] = vals[0][b][wl]; v01[b] = vals[0][b][wl + 1];
            v10[b] = vals[1][b][wl]; v11[b] = vals[1][b][wl + 1];
        }

        #pragma unroll 8
        for (int c = 0; c < kHID; ++c) {
            const float wd0 = valid ? Wd0[(size_t)c * kWMAX + w] : 0.0f;
            const float wd1 = valid ? Wd1[(size_t)c * kWMAX + w] : 0.0f;
            const float w00 = wconv_s[c * 4 + 0], w01 = wconv_s[c * 4 + 1];
            const float w10 = wconv_s[c * 4 + 2], w11 = wconv_s[c * 4 + 3];
            const float bc  = bconv_s[c];
            #pragma unroll
            for (int b = 0; b < 8; ++b) {
                float h = fmaf(v00[b], w00, fmaf(v01[b], w01,
                          fmaf(v10[b], w10, fmaf(v11[b], w11, bc))));
                h = fmaxf(h, 0.0f);
                acc0[b] = fmaf(wd0, h, acc0[b]);
                acc1[b] = fmaf(wd1, h, acc1[b]);
            }
        }
    }

    #pragma unroll
    for (int b = 0; b < 8; ++b) {
        float s0 = acc0[b], s1 = acc1[b];
        #pragma unroll
        for (int sft = 32; sft > 0; sft >>= 1) {
            s0 += __shfl_xor(s0, sft);
            s1 += __shfl_xor(s1, sft);
        }
        if (lane == 0) {
            atomicAdd(&emb[((size_t)b * kR + r) * kENC + o0],     s0);
            atomicAdd(&emb[((size_t)b * kR + r) * kENC + o0 + 1], s1);
        }
    }
}

// =====================================================================
// Kernel 2: single block. dinv/colsum-init + exclusive scan of cnt -> CSR offsets.
// =====================================================================
__global__ __launch_bounds__(256)
void k_scan(const float* __restrict__ deg, const int* __restrict__ cnt,
            float* __restrict__ dinv, float* __restrict__ colsum,
            int* __restrict__ off, int* __restrict__ woff)
{
    const int t = threadIdx.x;
    for (int i = t; i < kN; i += 256) {
        float d = deg[i] + 1.0f;         // self loop
        dinv[i]   = rsqrtf(d);
        colsum[i] = 1.0f / d;            // dinv^2 self term
    }
    __shared__ int cl[kN];
    for (int i = t; i < kN; i += 256) cl[i] = cnt[i];
    __syncthreads();

    // per-thread chunk of 28
    int loc[28];
    int s = 0;
    const int base = t * 28;
    #pragma unroll
    for (int k = 0; k < 28; ++k) { loc[k] = s; s += cl[base + k]; }

    __shared__ int sa[256], sb[256];
    sa[t] = s;
    __syncthreads();
    int* in = sa; int* out = sb;
    for (int d = 1; d < 256; d <<= 1) {
        out[t] = in[t] + ((t >= d) ? in[t - d] : 0);
        __syncthreads();
        int* tmp = in; in = out; out = tmp;
    }
    const int incl = in[t];
    const int excl = incl - s;
    #pragma unroll
    for (int k = 0; k < 28; ++k) {
        off[base + k]  = excl + loc[k];
        woff[base + k] = excl + loc[k];
    }
    if (t == 255) off[kN] = incl;   // = kE
}

// =====================================================================
// Kernel 3: per-edge norm + CSR fill + colsum accumulation.
// =====================================================================
__global__ __launch_bounds__(256)
void k_fill(const int* __restrict__ ei, const float* __restrict__ edge_w,
            const float* __restrict__ dinv, int* __restrict__ woff,
            int* __restrict__ csrc, float* __restrict__ cnrm,
            float* __restrict__ colsum)
{
    int e = blockIdx.x * 256 + threadIdx.x;
    if (e >= kE) return;
    const int s = ei[e], t = ei[kE + e];
    const float nm = dinv[s] * sigmoidf_(edge_w[e % kEPS]) * dinv[t];
    const int p = atomicAdd(&woff[t], 1);
    csrc[p] = s;
    cnrm[p] = nm;
    atomicAdd(&colsum[s], nm);
}

// =====================================================================
// Kernel 4: xw1 = (emb + bdec) @ Wg1
// =====================================================================
__global__ __launch_bounds__(256)
void k_xw1(const float* __restrict__ emb, const float* __restrict__ bdec,
           const float* __restrict__ Wg1, float* __restrict__ xw1)
{
    int t = blockIdx.x * 256 + threadIdx.x;
    int i = t >> 6, f = t & 63;
    int r = i % kR;
    float s = 0.0f;
    #pragma unroll
    for (int o = 0; o < kENC; ++o)
        s = fmaf(emb[i * kENC + o] + bdec[r * kENC + o], Wg1[o * kGH + f], s);
    xw1[t] = s;
}

// =====================================================================
// Kernel 5: fused aggregate(layer1) + ReLU + xw2(Wg2 in LDS) + weighted pool.
// 448 blocks x 256 threads (4 waves); block owns 16 consecutive nodes (one b).
// =====================================================================
__global__ __launch_bounds__(256)
void k_agg(const float* __restrict__ xw1, const int* __restrict__ off,
           const int* __restrict__ csrc, const float* __restrict__ cnrm,
           const float* __restrict__ dinv, const float* __restrict__ colsum,
           const float* __restrict__ bg1, const float* __restrict__ Wg2,
           float* __restrict__ pooled)
{
    const int tid  = threadIdx.x;
    const int wave = tid >> 6, f = tid & 63;

    __shared__ float wg2s[kGH * kGH];     // 16 KB
    __shared__ float hrow[4][kGH];
    __shared__ float pool_s[kGH];

    for (int i = tid; i < kGH * kGH; i += 256) wg2s[i] = Wg2[i];
    if (tid < kGH) pool_s[tid] = 0.0f;
    __syncthreads();

    const int j0 = blockIdx.x * 16;
    #pragma unroll
    for (int q = 0; q < 4; ++q) {
        const int j = j0 + wave * 4 + q;
        const float di = dinv[j];
        float a = fmaf(di * di, xw1[(size_t)j * kGH + f], bg1[f]);
        const int pb = off[j], pe = off[j + 1];
        for (int p = pb; p < pe; ++p) {
            const int s = csrc[p];
            const float nm = cnrm[p];
            a = fmaf(nm, xw1[(size_t)s * kGH + f], a);
        }
        a = fmaxf(a, 0.0f);
        hrow[wave][f] = a;               // wave-synchronous
        float s2 = 0.0f;
        #pragma unroll 8
        for (int f2 = 0; f2 < kGH; ++f2)
            s2 = fmaf(hrow[wave][f2], wg2s[f2 * kGH + f], s2);
        atomicAdd(&pool_s[f], colsum[j] * s2);
    }
    __syncthreads();
    if (tid < kGH) {
        const int b = j0 / kR;
        atomicAdd(&pooled[b * kGH + tid], pool_s[tid]);
    }
}

// =====================================================================
// Kernel 6: head — logits + softmax (tiny).
// =====================================================================
__global__ __launch_bounds__(128)
void k_head(const float* __restrict__ pooled, const float* __restrict__ bg2,
            const float* __restrict__ Wl, const float* __restrict__ bl,
            float* __restrict__ out)
{
    const int t = threadIdx.x;
    __shared__ float lgs[kB * kNCLS];
    if (t < kB * kNCLS) {
        const int b = t / kNCLS, c = t % kNCLS;
        float s = bl[c];
        for (int g = 0; g < kGH; ++g) {
            const float pg = bg2[g] + pooled[b * kGH + g] * (1.0f / kR);
            s = fmaf(pg, Wl[g * kNCLS + c], s);
        }
        lgs[t] = s;
    }
    __syncthreads();
    if (t < kB) {
        float mx = lgs[t * kNCLS];
        for (int j = 1; j < kNCLS; ++j) mx = fmaxf(mx, lgs[t * kNCLS + j]);
        float ssum = 0.0f, ex[kNCLS];
        for (int j = 0; j < kNCLS; ++j) { ex[j] = expf(lgs[t * kNCLS + j] - mx); ssum += ex[j]; }
        for (int j = 0; j < kNCLS; ++j) out[t * kNCLS + j] = ex[j] / ssum;
    }
}

extern "C" void kernel_launch(void* const* d_in, const int* in_sizes, int n_in,
                              void* d_out, int out_size, void* d_ws, size_t ws_size,
                              hipStream_t stream)
{
    const float* x      = (const float*)d_in[0];
    const int*   ei     = (const int*)d_in[1];
    const int*   idx    = (const int*)d_in[3];
    const float* Wconv  = (const float*)d_in[4];
    const float* bconv  = (const float*)d_in[5];
    const float* Wdec   = (const float*)d_in[6];
    const float* bdec   = (const float*)d_in[7];
    const float* edge_w = (const float*)d_in[8];
    const float* Wg1    = (const float*)d_in[9];
    const float* bg1    = (const float*)d_in[10];
    const float* Wg2    = (const float*)d_in[11];
    const float* bg2    = (const float*)d_in[12];
    const float* Wl     = (const float*)d_in[13];
    const float* bl     = (const float*)d_in[14];

    float* ws     = (float*)d_ws;
    float* emb    = ws + OFF_EMB;
    float* deg    = ws + OFF_DEG;
    int*   cnt    = (int*)(ws + OFF_CNT);
    float* pooled = ws + OFF_POOL;
    float* dinv   = ws + OFF_DINV;
    float* colsum = ws + OFF_CSUM;
    int*   off    = (int*)(ws + OFF_OFFS);
    int*   woff   = (int*)(ws + OFF_WOFF);
    int*   csrc   = (int*)(ws + OFF_CSRC);
    float* cnrm   = ws + OFF_CNRM;
    float* xw1    = ws + OFF_XW1;

    hipMemsetAsync(ws, 0, kMEMSET_FLOATS * sizeof(float), stream);

    const int degBlocks = (kE + 319) / 320;
    k_conv_emb<<<kNCHUNK + degBlocks, 320, 0, stream>>>(x, idx, Wconv, bconv, Wdec,
                                                        ei, edge_w, emb, deg, cnt);

    k_xw1 <<<kN * kGH / 256, 256, 0, stream>>>(emb, bdec, Wg1, xw1);
    k_scan<<<1, 256, 0, stream>>>(deg, cnt, dinv, colsum, off, woff);
    k_fill<<<(kE + 255) / 256, 256, 0, stream>>>(ei, edge_w, dinv, woff, csrc, cnrm, colsum);
    k_agg <<<kN / 16, 256, 0, stream>>>(xw1, off, csrc, cnrm, dinv, colsum, bg1, Wg2, pooled);
    k_head<<<1, 128, 0, stream>>>(pooled, bg2, Wl, bl, (float*)d_out);
}

// Round 5
// 122.318 us; speedup vs baseline: 2.6452x; 1.0497x over previous
//
#include <hip/hip_runtime.h>

// ---- problem constants ----
static constexpr int kR    = 896;
static constexpr int kLMAX = 510;
static constexpr int kWMAX = 509;
static constexpr int kHID  = 32;
static constexpr int kENC  = 10;
static constexpr int kGH   = 64;
static constexpr int kNCLS = 10;
static constexpr int kB    = 8;
static constexpr int kEPS  = 7168;
static constexpr int kN    = kB * kR;
static constexpr int kE    = kB * kEPS;
static constexpr int kPAD  = 3 * 256 * 256;

// band[r] = 4*i+1, i = ring index within its (m, by, bx) block.
constexpr int band_of(int r) {
    int i = (r < 128) ? r : (r < 384) ? ((r - 128) & 63) : ((r - 384) & 31);
    return 4 * i + 1;
}
__device__ __forceinline__ int band_dev(int r) {
    int i = (r < 128) ? r : (r < 384) ? ((r - 128) & 63) : ((r - 384) & 31);
    return 4 * i + 1;
}

static constexpr int kCHUNK = 128;
constexpr int count_chunks() {
    int n = 0;
    for (int r = 0; r < kR; ++r) n += (band_of(r) + kCHUNK - 1) / kCHUNK;
    return n;
}
static constexpr int kNCHUNK = count_chunks();   // 1216
static_assert(kNCHUNK == 1216, "chunk count");

struct CE { short r; short w0; };
struct Tab { CE e[kNCHUNK]; };
constexpr Tab make_tab() {
    Tab t{};
    int n = 0;
    for (int r = 0; r < kR; ++r)
        for (int w0 = 0; w0 < band_of(r); w0 += kCHUNK) {
            t.e[n].r = (short)r; t.e[n].w0 = (short)w0; ++n;
        }
    return t;
}
__device__ __constant__ Tab g_tab = make_tab();

// ---- workspace layout (floats; ints stored in same region) ----
static constexpr size_t OFF_EMB  = 0;                       // 71680 f
static constexpr size_t OFF_DEG  = OFF_EMB + 71680;         // 7168 f
static constexpr size_t OFF_CNT  = OFF_DEG + 7168;          // 7168 int
static constexpr size_t OFF_POOL = OFF_CNT + 7168;          // 512 f
static constexpr size_t kMEMSET_FLOATS = OFF_POOL + 512;    // 86528 (zeroed)
static constexpr size_t OFF_DINV = kMEMSET_FLOATS;          // 7168 f
static constexpr size_t OFF_CSUM = OFF_DINV + 7168;         // 7168 f
static constexpr size_t OFF_OFFS = OFF_CSUM + 7168;         // 7169 int
static constexpr size_t OFF_WOFF = OFF_OFFS + 7169;         // 7169 int
static constexpr size_t OFF_CSRC = OFF_WOFF + 7169;         // 57344 int
static constexpr size_t OFF_CNRM = OFF_CSRC + 57344;        // 57344 f
static constexpr size_t OFF_XW1  = OFF_CNRM + 57344;        // 458752 f
static constexpr size_t OFF_XT   = (OFF_XW1 + 458752 + 7) & ~(size_t)7;  // kPAD*8 f, 32B-aligned

__device__ __forceinline__ float sigmoidf_(float v) { return 1.0f / (1.0f + expf(-v)); }

// =====================================================================
// Kernel 0: transpose x -> xt[j][b] (float8 per pixel), + edge deg/cnt.
// blocks [0,768): transpose. blocks [768, 768+224): edge atomics.
// =====================================================================
__global__ __launch_bounds__(256)
void k_xpose(const float* __restrict__ x, const int* __restrict__ ei,
             const float* __restrict__ edge_w,
             float* __restrict__ xt, float* __restrict__ deg, int* __restrict__ cnt)
{
    const int bid = blockIdx.x;
    const int tid = threadIdx.x;
    if (bid < kPAD / 256) {
        const int j = bid * 256 + tid;
        float4 lo, hi;
        lo.x = x[(size_t)0 * kPAD + j]; lo.y = x[(size_t)1 * kPAD + j];
        lo.z = x[(size_t)2 * kPAD + j]; lo.w = x[(size_t)3 * kPAD + j];
        hi.x = x[(size_t)4 * kPAD + j]; hi.y = x[(size_t)5 * kPAD + j];
        hi.z = x[(size_t)6 * kPAD + j]; hi.w = x[(size_t)7 * kPAD + j];
        float4* dst = (float4*)&xt[(size_t)j * 8];
        dst[0] = lo; dst[1] = hi;
    } else {
        const int e = (bid - kPAD / 256) * 256 + tid;
        if (e < kE) {
            const int t = ei[kE + e];
            atomicAdd(&deg[t], sigmoidf_(edge_w[e % kEPS]));
            atomicAdd(&cnt[t], 1);
        }
    }
}

// =====================================================================
// Kernel 1: band-aware fused conv + decoder; x gathered from xt (32B/entry).
// =====================================================================
__global__ __launch_bounds__(320, 4)
void k_conv_emb(const float* __restrict__ xt, const int* __restrict__ idx,
                const float* __restrict__ Wconv, const float* __restrict__ bconv,
                const float* __restrict__ Wdec, float* __restrict__ emb)
{
    const int bid = blockIdx.x;
    const int tid = threadIdx.x;

    const int r     = g_tab.e[bid].r;
    const int w0    = g_tab.e[bid].w0;
    const int bandr = band_dev(r);
    const int wc    = min(kCHUNK, bandr - w0);

    __shared__ float vals[2][kB][kCHUNK + 1];
    __shared__ float wconv_s[kHID * 4];
    __shared__ float bconv_s[kHID];

    if (tid < 128) wconv_s[tid] = Wconv[r * 128 + tid];
    else if (tid < 160) bconv_s[tid - 128] = bconv[r * kHID + (tid - 128)];

    if (tid < 2 * (kCHUNK + 1)) {
        const int hh = tid >= (kCHUNK + 1);
        const int li = tid - hh * (kCHUNK + 1);
        const int j = (li <= wc) ? idx[(r * 2 + hh) * kLMAX + w0 + li] : kPAD;
        float4 lo = {0, 0, 0, 0}, hi = {0, 0, 0, 0};
        if ((unsigned)j < (unsigned)kPAD) {
            const float4* src = (const float4*)&xt[(size_t)j * 8];
            lo = src[0]; hi = src[1];
        }
        vals[hh][0][li] = lo.x; vals[hh][1][li] = lo.y;
        vals[hh][2][li] = lo.z; vals[hh][3][li] = lo.w;
        vals[hh][4][li] = hi.x; vals[hh][5][li] = hi.y;
        vals[hh][6][li] = hi.z; vals[hh][7][li] = hi.w;
    }
    __syncthreads();

    const int wave = tid >> 6, lane = tid & 63;
    const int o0 = wave * 2;
    const float* Wd0 = Wdec + ((size_t)(r * kENC + o0) * kHID) * kWMAX;
    const float* Wd1 = Wd0 + (size_t)kHID * kWMAX;

    float acc0[8] = {0,0,0,0,0,0,0,0}, acc1[8] = {0,0,0,0,0,0,0,0};

    #pragma unroll
    for (int st = 0; st < 2; ++st) {
        const int wl = st * 64 + lane;
        if (st * 64 >= wc) break;
        const bool valid = (wl < wc);
        const int w = w0 + wl;

        float v00[8], v01[8], v10[8], v11[8];
        #pragma unroll
        for (int b = 0; b < 8; ++b) {
            v00[b] = vals[0][b][wl]; v01[b] = vals[0][b][wl + 1];
            v10[b] = vals[1][b][wl]; v11[b] = vals[1][b][wl + 1];
        }

        #pragma unroll 8
        for (int c = 0; c < kHID; ++c) {
            const float wd0 = valid ? Wd0[(size_t)c * kWMAX + w] : 0.0f;
            const float wd1 = valid ? Wd1[(size_t)c * kWMAX + w] : 0.0f;
            const float w00 = wconv_s[c * 4 + 0], w01 = wconv_s[c * 4 + 1];
            const float w10 = wconv_s[c * 4 + 2], w11 = wconv_s[c * 4 + 3];
            const float bc  = bconv_s[c];
            #pragma unroll
            for (int b = 0; b < 8; ++b) {
                float h = fmaf(v00[b], w00, fmaf(v01[b], w01,
                          fmaf(v10[b], w10, fmaf(v11[b], w11, bc))));
                h = fmaxf(h, 0.0f);
                acc0[b] = fmaf(wd0, h, acc0[b]);
                acc1[b] = fmaf(wd1, h, acc1[b]);
            }
        }
    }

    #pragma unroll
    for (int b = 0; b < 8; ++b) {
        float s0 = acc0[b], s1 = acc1[b];
        #pragma unroll
        for (int sft = 32; sft > 0; sft >>= 1) {
            s0 += __shfl_xor(s0, sft);
            s1 += __shfl_xor(s1, sft);
        }
        if (lane == 0) {
            atomicAdd(&emb[((size_t)b * kR + r) * kENC + o0],     s0);
            atomicAdd(&emb[((size_t)b * kR + r) * kENC + o0 + 1], s1);
        }
    }
}

// =====================================================================
// Kernel 2: block 0 = scan (dinv/colsum init + CSR offsets);
//           blocks 1.. = xw1 = (emb + bdec) @ Wg1.
// =====================================================================
__global__ __launch_bounds__(256)
void k_scanxw1(const float* __restrict__ deg, const int* __restrict__ cnt,
               float* __restrict__ dinv, float* __restrict__ colsum,
               int* __restrict__ off, int* __restrict__ woff,
               const float* __restrict__ emb, const float* __restrict__ bdec,
               const float* __restrict__ Wg1, float* __restrict__ xw1)
{
    const int bid = blockIdx.x;
    const int t = threadIdx.x;
    if (bid > 0) {
        const int tt = (bid - 1) * 256 + t;
        const int i = tt >> 6, f = tt & 63;
        const int r = i % kR;
        float s = 0.0f;
        #pragma unroll
        for (int o = 0; o < kENC; ++o)
            s = fmaf(emb[i * kENC + o] + bdec[r * kENC + o], Wg1[o * kGH + f], s);
        xw1[tt] = s;
        return;
    }

    for (int i = t; i < kN; i += 256) {
        float d = deg[i] + 1.0f;
        dinv[i]   = rsqrtf(d);
        colsum[i] = 1.0f / d;
    }
    __shared__ int cl[kN];
    for (int i = t; i < kN; i += 256) cl[i] = cnt[i];
    __syncthreads();

    int loc[28];
    int s = 0;
    const int base = t * 28;
    #pragma unroll
    for (int k = 0; k < 28; ++k) { loc[k] = s; s += cl[base + k]; }

    __shared__ int sa[256], sb[256];
    sa[t] = s;
    __syncthreads();
    int* in = sa; int* out = sb;
    for (int d = 1; d < 256; d <<= 1) {
        out[t] = in[t] + ((t >= d) ? in[t - d] : 0);
        __syncthreads();
        int* tmp = in; in = out; out = tmp;
    }
    const int incl = in[t];
    const int excl = incl - s;
    #pragma unroll
    for (int k = 0; k < 28; ++k) {
        off[base + k]  = excl + loc[k];
        woff[base + k] = excl + loc[k];
    }
    if (t == 255) off[kN] = incl;
}

// =====================================================================
// Kernel 3: per-edge norm + CSR fill + colsum accumulation.
// =====================================================================
__global__ __launch_bounds__(256)
void k_fill(const int* __restrict__ ei, const float* __restrict__ edge_w,
            const float* __restrict__ dinv, int* __restrict__ woff,
            int* __restrict__ csrc, float* __restrict__ cnrm,
            float* __restrict__ colsum)
{
    int e = blockIdx.x * 256 + threadIdx.x;
    if (e >= kE) return;
    const int s = ei[e], t = ei[kE + e];
    const float nm = dinv[s] * sigmoidf_(edge_w[e % kEPS]) * dinv[t];
    const int p = atomicAdd(&woff[t], 1);
    csrc[p] = s;
    cnrm[p] = nm;
    atomicAdd(&colsum[s], nm);
}

// =====================================================================
// Kernel 4: fused aggregate(layer1) + ReLU + xw2(Wg2 in LDS) + weighted pool.
// CSR edge loop software-pipelined 1-deep.
// =====================================================================
__global__ __launch_bounds__(256)
void k_agg(const float* __restrict__ xw1, const int* __restrict__ off,
           const int* __restrict__ csrc, const float* __restrict__ cnrm,
           const float* __restrict__ dinv, const float* __restrict__ colsum,
           const float* __restrict__ bg1, const float* __restrict__ Wg2,
           float* __restrict__ pooled)
{
    const int tid  = threadIdx.x;
    const int wave = tid >> 6, f = tid & 63;

    __shared__ float wg2s[kGH * kGH];
    __shared__ float hrow[4][kGH];
    __shared__ float pool_s[kGH];

    for (int i = tid; i < kGH * kGH; i += 256) wg2s[i] = Wg2[i];
    if (tid < kGH) pool_s[tid] = 0.0f;
    __syncthreads();

    const int j0 = blockIdx.x * 16;
    #pragma unroll
    for (int q = 0; q < 4; ++q) {
        const int j = j0 + wave * 4 + q;
        const float di = dinv[j];
        float a = fmaf(di * di, xw1[(size_t)j * kGH + f], bg1[f]);
        const int pb = off[j], pe = off[j + 1];
        int   sC = 0; float nC = 0.0f;
        if (pb < pe) { sC = csrc[pb]; nC = cnrm[pb]; }
        for (int p = pb; p < pe; ++p) {
            int sN = sC; float nN = 0.0f;
            if (p + 1 < pe) { sN = csrc[p + 1]; nN = cnrm[p + 1]; }
            a = fmaf(nC, xw1[(size_t)sC * kGH + f], a);
            sC = sN; nC = nN;
        }
        a = fmaxf(a, 0.0f);
        hrow[wave][f] = a;
        float s2 = 0.0f;
        #pragma unroll 8
        for (int f2 = 0; f2 < kGH; ++f2)
            s2 = fmaf(hrow[wave][f2], wg2s[f2 * kGH + f], s2);
        atomicAdd(&pool_s[f], colsum[j] * s2);
    }
    __syncthreads();
    if (tid < kGH) {
        const int b = j0 / kR;
        atomicAdd(&pooled[b * kGH + tid], pool_s[tid]);
    }
}

// =====================================================================
// Kernel 5: head — logits + softmax (tiny).
// =====================================================================
__global__ __launch_bounds__(128)
void k_head(const float* __restrict__ pooled, const float* __restrict__ bg2,
            const float* __restrict__ Wl, const float* __restrict__ bl,
            float* __restrict__ out)
{
    const int t = threadIdx.x;
    __shared__ float lgs[kB * kNCLS];
    if (t < kB * kNCLS) {
        const int b = t / kNCLS, c = t % kNCLS;
        float s = bl[c];
        for (int g = 0; g < kGH; ++g) {
            const float pg = bg2[g] + pooled[b * kGH + g] * (1.0f / kR);
            s = fmaf(pg, Wl[g * kNCLS + c], s);
        }
        lgs[t] = s;
    }
    __syncthreads();
    if (t < kB) {
        float mx = lgs[t * kNCLS];
        for (int j = 1; j < kNCLS; ++j) mx = fmaxf(mx, lgs[t * kNCLS + j]);
        float ssum = 0.0f, ex[kNCLS];
        for (int j = 0; j < kNCLS; ++j) { ex[j] = expf(lgs[t * kNCLS + j] - mx); ssum += ex[j]; }
        for (int j = 0; j < kNCLS; ++j) out[t * kNCLS + j] = ex[j] / ssum;
    }
}

extern "C" void kernel_launch(void* const* d_in, const int* in_sizes, int n_in,
                              void* d_out, int out_size, void* d_ws, size_t ws_size,
                              hipStream_t stream)
{
    const float* x      = (const float*)d_in[0];
    const int*   ei     = (const int*)d_in[1];
    const int*   idx    = (const int*)d_in[3];
    const float* Wconv  = (const float*)d_in[4];
    const float* bconv  = (const float*)d_in[5];
    const float* Wdec   = (const float*)d_in[6];
    const float* bdec   = (const float*)d_in[7];
    const float* edge_w = (const float*)d_in[8];
    const float* Wg1    = (const float*)d_in[9];
    const float* bg1    = (const float*)d_in[10];
    const float* Wg2    = (const float*)d_in[11];
    const float* bg2    = (const float*)d_in[12];
    const float* Wl     = (const float*)d_in[13];
    const float* bl     = (const float*)d_in[14];

    float* ws     = (float*)d_ws;
    float* emb    = ws + OFF_EMB;
    float* deg    = ws + OFF_DEG;
    int*   cnt    = (int*)(ws + OFF_CNT);
    float* pooled = ws + OFF_POOL;
    float* dinv   = ws + OFF_DINV;
    float* colsum = ws + OFF_CSUM;
    int*   off    = (int*)(ws + OFF_OFFS);
    int*   woff   = (int*)(ws + OFF_WOFF);
    int*   csrc   = (int*)(ws + OFF_CSRC);
    float* cnrm   = ws + OFF_CNRM;
    float* xw1    = ws + OFF_XW1;
    float* xt     = ws + OFF_XT;

    hipMemsetAsync(ws, 0, kMEMSET_FLOATS * sizeof(float), stream);

    k_xpose<<<kPAD / 256 + (kE + 255) / 256, 256, 0, stream>>>(x, ei, edge_w, xt, deg, cnt);

    k_conv_emb<<<kNCHUNK, 320, 0, stream>>>(xt, idx, Wconv, bconv, Wdec, emb);

    k_scanxw1<<<1 + kN * kGH / 256, 256, 0, stream>>>(deg, cnt, dinv, colsum, off, woff,
                                                      emb, bdec, Wg1, xw1);
    k_fill<<<(kE + 255) / 256, 256, 0, stream>>>(ei, edge_w, dinv, woff, csrc, cnrm, colsum);
    k_agg <<<kN / 16, 256, 0, stream>>>(xw1, off, csrc, cnrm, dinv, colsum, bg1, Wg2, pooled);
    k_head<<<1, 128, 0, stream>>>(pooled, bg2, Wl, bl, (float*)d_out);
}